// Round 1
// baseline (6718.935 us; speedup 1.0000x reference)
//
#include <hip/hip_runtime.h>
#include <math.h>

// One 64-thread block (one wave) per matrix.
// Pipeline per matrix: load 32x32 SPD -> Jacobi eigensolve (n=32) ->
// M = V log(L) V^T -> maxpool 4x4 s2 -> 15x15 (padded to 16) ->
// Jacobi eigensolve (n=16) -> out = V2 exp(L2) V2^T (15x15).

constexpr int N1 = 32, LD1 = 33;   // padded leading dim: no LDS bank conflicts
constexpr int N2 = 16, LD2 = 17;
constexpr int SW1 = 10;            // sweeps for n=32 Jacobi
constexpr int SW2 = 8;             // sweeps for n=16 Jacobi

__global__ __launch_bounds__(64)
void spd_logeig_pool_expeig(const float* __restrict__ x,
                            float* __restrict__ out, int n_mat)
{
    __shared__ float A [N1 * LD1];   // input matrix, then M = V log(L) V^T
    __shared__ float V [N1 * LD1];   // eigenvectors stage 1
    __shared__ float P [N2 * LD2];   // pooled matrix (padded 16x16, zeros)
    __shared__ float V2[N2 * LD2];   // eigenvectors stage 2
    __shared__ float lam[N1];        // eigenvalue scratch

    const int tid = threadIdx.x;
    const int mat = blockIdx.x;
    if (mat >= n_mat) return;
    const float* xm = x + (size_t)mat * (N1 * N1);

    // ---- load A, V = I ----
    for (int idx = tid; idx < N1 * N1; idx += 64) {
        int r = idx >> 5, c = idx & 31;
        A[r * LD1 + c] = xm[idx];
        V[r * LD1 + c] = (r == c) ? 1.0f : 0.0f;
    }
    __syncthreads();

    // ---- stage 1: two-sided Jacobi, n=32, tournament ordering ----
    {
        const int pairId = tid >> 2;     // 16 disjoint pairs per step
        const int sub    = tid & 3;      // 4 threads per pair, 8 rows/cols each
        for (int sweep = 0; sweep < SW1; ++sweep) {
            for (int rr = 0; rr < N1 - 1; ++rr) {
                int p, q;
                if (pairId == 0) { p = rr % (N1 - 1); q = N1 - 1; }
                else {
                    p = (rr + pairId) % (N1 - 1);
                    q = (rr + (N1 - 1) - pairId) % (N1 - 1);
                }
                if (p > q) { int t_ = p; p = q; q = t_; }

                // rotation params (computed redundantly by the pair's 4 threads)
                float apq = A[p * LD1 + q];
                float c, s;
                if (fabsf(apq) > 1e-30f) {
                    float app = A[p * LD1 + p];
                    float aqq = A[q * LD1 + q];
                    float theta = 0.5f * (aqq - app) / apq;
                    float t = 1.0f / (fabsf(theta) + sqrtf(theta * theta + 1.0f));
                    if (theta < 0.0f) t = -t;
                    c = 1.0f / sqrtf(t * t + 1.0f);
                    s = t * c;
                } else { c = 1.0f; s = 0.0f; }
                __syncthreads();

                // column rotation: A <- A G, V <- V G   (8 rows per thread)
                #pragma unroll
                for (int i = 0; i < 8; ++i) {
                    int row = (sub << 3) + i;
                    float ap = A[row * LD1 + p], aq = A[row * LD1 + q];
                    A[row * LD1 + p] = c * ap - s * aq;
                    A[row * LD1 + q] = s * ap + c * aq;
                    float vp = V[row * LD1 + p], vq = V[row * LD1 + q];
                    V[row * LD1 + p] = c * vp - s * vq;
                    V[row * LD1 + q] = s * vp + c * vq;
                }
                __syncthreads();

                // row rotation: A <- G^T A   (8 cols per thread)
                #pragma unroll
                for (int i = 0; i < 8; ++i) {
                    int col = (sub << 3) + i;
                    float pa = A[p * LD1 + col], qa = A[q * LD1 + col];
                    A[p * LD1 + col] = c * pa - s * qa;
                    A[q * LD1 + col] = s * pa + c * qa;
                }
                __syncthreads();
            }
        }
    }

    // eigenvalues (diag of converged A); spectrum >= 1 so log is safe
    if (tid < N1) lam[tid] = logf(A[tid * LD1 + tid]);
    __syncthreads();

    // ---- reconstruct M = V diag(log L) V^T into A (4x4 register blocks) ----
    {
        const int bi = tid >> 3, bj = tid & 7;     // 8x8 grid of 4x4 blocks
        float m[4][4];
        #pragma unroll
        for (int a = 0; a < 4; ++a)
            #pragma unroll
            for (int b = 0; b < 4; ++b) m[a][b] = 0.0f;
        for (int k = 0; k < N1; ++k) {
            float lk = lam[k];
            float vi[4], vj[4];
            #pragma unroll
            for (int a = 0; a < 4; ++a) vi[a] = V[(bi * 4 + a) * LD1 + k] * lk;
            #pragma unroll
            for (int b = 0; b < 4; ++b) vj[b] = V[(bj * 4 + b) * LD1 + k];
            #pragma unroll
            for (int a = 0; a < 4; ++a)
                #pragma unroll
                for (int b = 0; b < 4; ++b)
                    m[a][b] += vi[a] * vj[b];
        }
        __syncthreads();
        #pragma unroll
        for (int a = 0; a < 4; ++a)
            #pragma unroll
            for (int b = 0; b < 4; ++b)
                A[(bi * 4 + a) * LD1 + (bj * 4 + b)] = m[a][b];
    }
    __syncthreads();

    // ---- maxpool 4x4 stride 2 -> P (padded 16x16 with zeros); V2 = I ----
    for (int idx = tid; idx < N2 * LD2; idx += 64) P[idx] = 0.0f;
    for (int idx = tid; idx < N2 * N2; idx += 64) {
        int r = idx >> 4, c = idx & 15;
        V2[r * LD2 + c] = (r == c) ? 1.0f : 0.0f;
    }
    __syncthreads();
    for (int idx = tid; idx < 15 * 15; idx += 64) {
        int oi = idx / 15, oj = idx % 15;
        float mx = -INFINITY;
        #pragma unroll
        for (int di = 0; di < 4; ++di)
            #pragma unroll
            for (int dj = 0; dj < 4; ++dj)
                mx = fmaxf(mx, A[(2 * oi + di) * LD1 + (2 * oj + dj)]);
        P[oi * LD2 + oj] = mx;
    }
    __syncthreads();

    // ---- stage 2: two-sided Jacobi, n=16 (index 15 is a decoupled dummy) ----
    {
        const int pairId = tid >> 3;     // 8 pairs
        const int sub    = tid & 7;      // 8 threads per pair, 2 rows/cols each
        for (int sweep = 0; sweep < SW2; ++sweep) {
            for (int rr = 0; rr < N2 - 1; ++rr) {
                int p, q;
                if (pairId == 0) { p = rr % (N2 - 1); q = N2 - 1; }
                else {
                    p = (rr + pairId) % (N2 - 1);
                    q = (rr + (N2 - 1) - pairId) % (N2 - 1);
                }
                if (p > q) { int t_ = p; p = q; q = t_; }

                float apq = P[p * LD2 + q];
                float c, s;
                if (fabsf(apq) > 1e-30f) {
                    float app = P[p * LD2 + p];
                    float aqq = P[q * LD2 + q];
                    float theta = 0.5f * (aqq - app) / apq;
                    float t = 1.0f / (fabsf(theta) + sqrtf(theta * theta + 1.0f));
                    if (theta < 0.0f) t = -t;
                    c = 1.0f / sqrtf(t * t + 1.0f);
                    s = t * c;
                } else { c = 1.0f; s = 0.0f; }
                __syncthreads();

                #pragma unroll
                for (int i = 0; i < 2; ++i) {
                    int row = (sub << 1) + i;
                    float ap = P[row * LD2 + p], aq = P[row * LD2 + q];
                    P[row * LD2 + p] = c * ap - s * aq;
                    P[row * LD2 + q] = s * ap + c * aq;
                    float vp = V2[row * LD2 + p], vq = V2[row * LD2 + q];
                    V2[row * LD2 + p] = c * vp - s * vq;
                    V2[row * LD2 + q] = s * vp + c * vq;
                }
                __syncthreads();

                #pragma unroll
                for (int i = 0; i < 2; ++i) {
                    int col = (sub << 1) + i;
                    float pa = P[p * LD2 + col], qa = P[q * LD2 + col];
                    P[p * LD2 + col] = c * pa - s * qa;
                    P[q * LD2 + col] = s * pa + c * qa;
                }
                __syncthreads();
            }
        }
    }

    if (tid < N2) lam[tid] = expf(P[tid * LD2 + tid]);
    __syncthreads();

    // ---- out = V2 diag(exp L2) V2^T, top-left 15x15 only ----
    float* om = out + (size_t)mat * 225;
    for (int idx = tid; idx < 225; idx += 64) {
        int i = idx / 15, j = idx % 15;
        float acc = 0.0f;
        #pragma unroll
        for (int k = 0; k < N2; ++k)
            acc += V2[i * LD2 + k] * lam[k] * V2[j * LD2 + k];
        om[idx] = acc;
    }
}

extern "C" void kernel_launch(void* const* d_in, const int* in_sizes, int n_in,
                              void* d_out, int out_size, void* d_ws, size_t ws_size,
                              hipStream_t stream)
{
    const float* x = (const float*)d_in[0];
    float* out = (float*)d_out;
    const int n_mat = in_sizes[0] / (32 * 32);   // 2048*16 = 32768
    dim3 grid(n_mat), block(64);
    hipLaunchKernelGGL(spd_logeig_pool_expeig, grid, block, 0, stream,
                       x, out, n_mat);
}

// Round 2
// 2406.867 us; speedup vs baseline: 2.7916x; 2.7916x over previous
//
#include <hip/hip_runtime.h>
#include <math.h>

// One 64-thread wave per 32x32 SPD matrix.
// Stage 1: one-sided (Hestenes) Jacobi in REGISTERS, XOR pairing, shfl_xor
//          exchange. Converged columns b_j = lambda_j * u_j; no V needed.
// LogEig:  M = B diag(log(l)/l^2) B^T  (LDS, broadcast-friendly 4x4 blocks)
// MaxPool 4x4 s2 -> 15x15 (padded to 16 with exact zero dummy)
// Stage 2: same one-sided Jacobi on P + sigma*I (Gershgorin shift -> PD)
// ExpEig:  out = B2 diag(exp(l'-sigma)/l'^2) B2^T, 15x15.

constexpr int SW1 = 10;   // sweeps, stage 1 (n=32)
constexpr int SW2 = 8;    // sweeps, stage 2 (n=16)

__global__ __launch_bounds__(64)
void spd_logeig_pool_expeig(const float* __restrict__ x,
                            float* __restrict__ out, int n_mat)
{
    // LDS regions (floats). Bl dies before Pl/B2/w2 come alive (same space).
    __shared__ float sm[2144];
    float* const Bl = sm;            // [32][33]   stage-1 columns
    float* const Ml = sm + 1056;     // [32][33]   M = log-eig matrix
    float* const wl = sm + 2112;     // [32]
    float* const Pl = sm;            // [16][17]   pooled (padded, zeros)
    float* const B2 = sm + 288;      // [16][17]   stage-2 columns
    float* const w2 = sm + 560;      // [16]

    const int tid = threadIdx.x;
    const int mat = blockIdx.x;
    if (mat >= n_mat) return;
    const int j = tid & 31;          // column
    const int h = tid >> 5;          // row half: rows 16h .. 16h+15
    const float* __restrict__ xm = x + (size_t)mat * 1024;

    // ---- load column j (coalesced: lanes 0..31 and 32..63 each contiguous) ----
    float b[16];
    #pragma unroll
    for (int r = 0; r < 16; ++r)
        b[r] = xm[(16 * h + r) * 32 + j];

    float alpha;   // ||b_j||^2, replicated in both halves
    {
        float s = 0.f;
        #pragma unroll
        for (int r = 0; r < 16; ++r) s = fmaf(b[r], b[r], s);
        alpha = s + __shfl_xor(s, 32);
    }

    // ---- stage 1: one-sided Jacobi, pairs (j, j^m), m = 1..31 ----
    for (int sweep = 0; sweep < SW1; ++sweep) {
        for (int m = 1; m < 32; ++m) {
            const int hb = 31 - __clz(m);            // highest bit of m
            const bool isP = ((j >> hb) & 1) == 0;   // smaller index of pair
            float pb[16];
            float gp = 0.f;
            #pragma unroll
            for (int r = 0; r < 16; ++r) {
                pb[r] = __shfl_xor(b[r], m);         // partner column chunk
                gp = fmaf(b[r], pb[r], gp);
            }
            const float gam   = gp + __shfl_xor(gp, 32);   // b_p . b_q
            const float apart = __shfl_xor(alpha, m);
            // d = alpha_q - alpha_p  (bitwise identical in both lanes)
            const float d = isP ? (apart - alpha) : (alpha - apart);
            // t = sgn(d)*2*gam / (|d| + sqrt(d^2 + 4 gam^2)),  |t| <= 1
            const float denom = fabsf(d) + sqrtf(fmaf(d, d, 4.f * gam * gam));
            float t = __fdividef(2.f * gam, denom + 1e-30f);
            t = (d < 0.f) ? -t : t;
            const float c = rsqrtf(fmaf(t, t, 1.f));
            const float s = t * c;
            const float se = isP ? -s : s;
            #pragma unroll
            for (int r = 0; r < 16; ++r)
                b[r] = fmaf(se, pb[r], c * b[r]);
            alpha = fmaf(isP ? -t : t, gam, alpha);  // a' = a -+ t*gam
        }
        // refresh norm (kills rsqrt/track drift)
        float ss = 0.f;
        #pragma unroll
        for (int r = 0; r < 16; ++r) ss = fmaf(b[r], b[r], ss);
        alpha = ss + __shfl_xor(ss, 32);
    }

    // ---- write columns + weights; M = B diag(w) B^T ----
    #pragma unroll
    for (int r = 0; r < 16; ++r)
        Bl[(16 * h + r) * 33 + j] = b[r];
    if (h == 0) wl[j] = 0.5f * logf(alpha) / alpha;   // log(l)/l^2, l=sqrt(a)
    __syncthreads();

    {
        const int bi = tid >> 3, bj = tid & 7;        // 8x8 grid of 4x4 blocks
        float mm[4][4];
        #pragma unroll
        for (int a = 0; a < 4; ++a)
            #pragma unroll
            for (int cc = 0; cc < 4; ++cc) mm[a][cc] = 0.f;
        for (int k = 0; k < 32; ++k) {
            const float wk = wl[k];
            float vi[4], vj[4];
            #pragma unroll
            for (int a = 0; a < 4; ++a)  vi[a] = Bl[(bi * 4 + a) * 33 + k] * wk;
            #pragma unroll
            for (int cc = 0; cc < 4; ++cc) vj[cc] = Bl[(bj * 4 + cc) * 33 + k];
            #pragma unroll
            for (int a = 0; a < 4; ++a)
                #pragma unroll
                for (int cc = 0; cc < 4; ++cc)
                    mm[a][cc] = fmaf(vi[a], vj[cc], mm[a][cc]);
        }
        #pragma unroll
        for (int a = 0; a < 4; ++a)
            #pragma unroll
            for (int cc = 0; cc < 4; ++cc)
                Ml[(bi * 4 + a) * 33 + (bj * 4 + cc)] = mm[a][cc];
    }
    __syncthreads();

    // ---- maxpool 4x4 stride 2 -> Pl (16x16 padded with exact zeros) ----
    for (int idx = tid; idx < 16 * 17; idx += 64) Pl[idx] = 0.f;
    __syncthreads();
    for (int idx = tid; idx < 225; idx += 64) {
        const int oi = idx / 15, oj = idx % 15;
        float mx = -INFINITY;
        #pragma unroll
        for (int di = 0; di < 4; ++di)
            #pragma unroll
            for (int dj = 0; dj < 4; ++dj)
                mx = fmaxf(mx, Ml[(2 * oi + di) * 33 + (2 * oj + dj)]);
        Pl[oi * 17 + oj] = mx;
    }
    __syncthreads();

    // ---- Gershgorin shift: sigma = max row abs-sum + 1  =>  P+sigma*I is PD ----
    float g = 0.f;
    if (tid < 15) {
        #pragma unroll
        for (int cc = 0; cc < 15; ++cc) g += fabsf(Pl[tid * 17 + cc]);
    }
    #pragma unroll
    for (int msk = 1; msk < 64; msk <<= 1) g = fmaxf(g, __shfl_xor(g, msk));
    const float sigma = g + 1.0f;

    // ---- stage 2: one-sided Jacobi on P + sigma*I, n=16 ----
    const int j2 = tid & 15, h2 = tid >> 4;          // rows 4*h2 .. 4*h2+3
    float b2[4];
    #pragma unroll
    for (int r = 0; r < 4; ++r) {
        const int i = 4 * h2 + r;
        b2[r] = Pl[i * 17 + j2] + ((i == j2) ? sigma : 0.f);
    }
    float a2;
    {
        float s = 0.f;
        #pragma unroll
        for (int r = 0; r < 4; ++r) s = fmaf(b2[r], b2[r], s);
        s += __shfl_xor(s, 16);
        a2 = s + __shfl_xor(s, 32);
    }

    for (int sweep = 0; sweep < SW2; ++sweep) {
        for (int m = 1; m < 16; ++m) {
            const int hb = 31 - __clz(m);
            const bool isP = ((j2 >> hb) & 1) == 0;
            float pb[4];
            float gp = 0.f;
            #pragma unroll
            for (int r = 0; r < 4; ++r) {
                pb[r] = __shfl_xor(b2[r], m);
                gp = fmaf(b2[r], pb[r], gp);
            }
            gp += __shfl_xor(gp, 16);
            const float gam   = gp + __shfl_xor(gp, 32);
            const float apart = __shfl_xor(a2, m);
            const float d = isP ? (apart - a2) : (a2 - apart);
            const float denom = fabsf(d) + sqrtf(fmaf(d, d, 4.f * gam * gam));
            float t = __fdividef(2.f * gam, denom + 1e-30f);
            t = (d < 0.f) ? -t : t;
            const float c = rsqrtf(fmaf(t, t, 1.f));
            const float s = t * c;
            const float se = isP ? -s : s;
            #pragma unroll
            for (int r = 0; r < 4; ++r)
                b2[r] = fmaf(se, pb[r], c * b2[r]);
            a2 = fmaf(isP ? -t : t, gam, a2);
        }
        float ss = 0.f;
        #pragma unroll
        for (int r = 0; r < 4; ++r) ss = fmaf(b2[r], b2[r], ss);
        ss += __shfl_xor(ss, 16);
        a2 = ss + __shfl_xor(ss, 32);
    }

    #pragma unroll
    for (int r = 0; r < 4; ++r)
        B2[(4 * h2 + r) * 17 + j2] = b2[r];
    if (h2 == 0) {
        const float lamp = sqrtf(a2);                 // l' = l + sigma >= 1
        w2[j2] = expf(lamp - sigma) / a2;             // exp(l)/l'^2
    }
    __syncthreads();

    // ---- out = B2 diag(w2) B2^T, top-left 15x15 (dummy col contributes 0) ----
    float* __restrict__ om = out + (size_t)mat * 225;
    for (int idx = tid; idx < 225; idx += 64) {
        const int i = idx / 15, k = idx % 15;
        float acc = 0.f;
        #pragma unroll
        for (int cc = 0; cc < 16; ++cc)
            acc = fmaf(B2[i * 17 + cc] * w2[cc], B2[k * 17 + cc], acc);
        om[idx] = acc;
    }
}

extern "C" void kernel_launch(void* const* d_in, const int* in_sizes, int n_in,
                              void* d_out, int out_size, void* d_ws, size_t ws_size,
                              hipStream_t stream)
{
    const float* x = (const float*)d_in[0];
    float* out = (float*)d_out;
    const int n_mat = in_sizes[0] / (32 * 32);   // 2048*16 = 32768
    dim3 grid(n_mat), block(64);
    hipLaunchKernelGGL(spd_logeig_pool_expeig, grid, block, 0, stream,
                       x, out, n_mat);
}

// Round 5
// 1999.938 us; speedup vs baseline: 3.3596x; 1.2035x over previous
//
#include <hip/hip_runtime.h>
#include <math.h>

// One 64-thread wave per TWO matrices (lanes 0-31: mat A, 32-63: mat B).
// Stage 1: one-sided Jacobi, full column (32 rows) per lane, XOR pairing,
//          deferred column scaling (1 fma/elem update), early sweep exit.
//   NOTE: coef must use rf_OLD (1/f before this rotation) — computing it
//   after f/rf are updated inflates every rotation by 1/c (R3's NaN bug).
// Recon:   M = B diag(log(l)/l^2) B^T in 4x4 reg blocks, fused 2x2 pre-pool
//          maxes -> m2[16][17] (M never materialized).
// Pool:    out(oi,oj) = max of 4 m2 entries. Padded to 16 with zero dummy.
// Stage 2: same Jacobi on P + sigma*I (Gershgorin), 16-lane groups,
//          full column per lane. ExpEig -> 15x15 output.

constexpr int SW1 = 10;   // max sweeps stage 1 (early exit typical ~6-7)
constexpr int SW2 = 8;    // max sweeps stage 2

__global__ __launch_bounds__(64, 4)
void spd_logeig_pool_expeig(const float* __restrict__ x,
                            float* __restrict__ out, int n_blk)
{
    __shared__ float Bl[2 * 1056];   // [2][32*33] stage-1 columns (overlaid later)
    __shared__ float m2[2 * 272];    // [2][16*17] 2x2 block maxes
    __shared__ float wl[2 * 32];     // stage-1 weights

    float* const B2s = Bl;           // overlay: [2][16*17] stage-2 columns
    float* const w2s = Bl + 544;     // overlay: [2][16]   stage-2 weights

    const int tid  = threadIdx.x;
    const int j    = tid & 31;
    const int half = tid >> 5;
    const size_t matA = (size_t)blockIdx.x * 2;
    const float* __restrict__ xm = x + (matA + half) * 1024;

    // ---- load column j of this half's matrix ----
    float b[32];
    #pragma unroll
    for (int r = 0; r < 32; ++r) b[r] = xm[r * 32 + j];

    float alpha;
    {
        float s0 = 0.f, s1 = 0.f, s2 = 0.f, s3 = 0.f;
        #pragma unroll
        for (int r = 0; r < 32; r += 4) {
            s0 = fmaf(b[r],   b[r],   s0); s1 = fmaf(b[r+1], b[r+1], s1);
            s2 = fmaf(b[r+2], b[r+2], s2); s3 = fmaf(b[r+3], b[r+3], s3);
        }
        alpha = (s0 + s1) + (s2 + s3);
    }
    float f = 1.f, rf = 1.f;   // deferred column scale f and rf = 1/f

    // ---------------- stage 1: one-sided Jacobi, n=32 ----------------
    #pragma unroll 1
    for (int sweep = 0; sweep < SW1; ++sweep) {
        float offmax = -1.f;
        #pragma unroll 1
        for (int m = 1; m < 32; ++m) {
            const int hb = 31 - __clz(m);
            const bool isP = ((j >> hb) & 1) == 0;
            float pb[32];
            #pragma unroll
            for (int r = 0; r < 32; ++r) pb[r] = __shfl_xor(b[r], m);
            float g0 = 0.f, g1 = 0.f, g2a = 0.f, g3 = 0.f;
            #pragma unroll
            for (int r = 0; r < 32; r += 4) {
                g0  = fmaf(b[r],   pb[r],   g0);  g1 = fmaf(b[r+1], pb[r+1], g1);
                g2a = fmaf(b[r+2], pb[r+2], g2a); g3 = fmaf(b[r+3], pb[r+3], g3);
            }
            const float gp = (g0 + g1) + (g2a + g3);
            const float fq = __shfl_xor(f, m);
            const float aq = __shfl_xor(alpha, m);
            // gam/d bitwise-identical on both lanes of the pair
            const float gam = gp * (f * fq);
            const float d   = isP ? (aq - alpha) : (alpha - aq);
            const float tg  = gam + gam;
            const float den = sqrtf(fmaf(d, d, tg * tg)) + fabsf(d) + 1e-30f;
            float t = __fdividef(tg, den);
            t = (d < 0.f) ? -t : t;
            const float e = fmaf(t, t, 1.f);
            const float c = rsqrtf(e);
            float coef = t * (fq * rf);        // uses rf = 1/f_old  (THE FIX)
            coef = isP ? -coef : coef;
            f  *= c;                           // f_new = c * f_old
            rf *= e * c;                       // rf_new = rf_old / c
            offmax = fmaxf(offmax, fmaf(gam, gam, -1e-12f * (alpha * aq)));
            #pragma unroll
            for (int r = 0; r < 32; ++r) b[r] = fmaf(coef, pb[r], b[r]);
            alpha = fmaf(isP ? -t : t, gam, alpha);
        }
        // fold deferred scale, refresh true alpha
        #pragma unroll
        for (int r = 0; r < 32; ++r) b[r] *= f;
        {
            float s0 = 0.f, s1 = 0.f, s2 = 0.f, s3 = 0.f;
            #pragma unroll
            for (int r = 0; r < 32; r += 4) {
                s0 = fmaf(b[r],   b[r],   s0); s1 = fmaf(b[r+1], b[r+1], s1);
                s2 = fmaf(b[r+2], b[r+2], s2); s3 = fmaf(b[r+3], b[r+3], s3);
            }
            alpha = (s0 + s1) + (s2 + s3);
        }
        f = 1.f; rf = 1.f;
        if (__all(offmax <= 0.f)) break;
    }

    // ---- write columns + weights ----
    #pragma unroll
    for (int r = 0; r < 32; ++r) Bl[half * 1056 + r * 33 + j] = b[r];
    wl[half * 32 + j] = 0.5f * logf(alpha) / alpha;   // log(l)/l^2, l=sqrt(a)
    __syncthreads();

    // ---- M = B diag(w) B^T, 4x4 reg blocks, fused 2x2 pre-pool ----
    {
        const int bi = tid >> 3, bj = tid & 7;
        #pragma unroll 1
        for (int mm = 0; mm < 2; ++mm) {
            const float* __restrict__ B = Bl + mm * 1056;
            const float* __restrict__ w = wl + mm * 32;
            float acc[4][4];
            #pragma unroll
            for (int a = 0; a < 4; ++a)
                #pragma unroll
                for (int cc = 0; cc < 4; ++cc) acc[a][cc] = 0.f;
            #pragma unroll 2
            for (int k = 0; k < 32; ++k) {
                const float wk = w[k];
                float vi[4], vj[4];
                #pragma unroll
                for (int a = 0; a < 4; ++a)  vi[a] = B[(bi * 4 + a) * 33 + k] * wk;
                #pragma unroll
                for (int cc = 0; cc < 4; ++cc) vj[cc] = B[(bj * 4 + cc) * 33 + k];
                #pragma unroll
                for (int a = 0; a < 4; ++a)
                    #pragma unroll
                    for (int cc = 0; cc < 4; ++cc)
                        acc[a][cc] = fmaf(vi[a], vj[cc], acc[a][cc]);
            }
            #pragma unroll
            for (int u = 0; u < 2; ++u)
                #pragma unroll
                for (int v = 0; v < 2; ++v) {
                    const float mx =
                        fmaxf(fmaxf(acc[2*u][2*v],   acc[2*u][2*v+1]),
                              fmaxf(acc[2*u+1][2*v], acc[2*u+1][2*v+1]));
                    m2[mm * 272 + (2 * bi + u) * 17 + (2 * bj + v)] = mx;
                }
        }
    }
    __syncthreads();

    // ---------------- stage 2: n=16 (col 15 = zero dummy) ----------------
    const int j2  = tid & 15;
    const int grp = tid >> 4;            // groups 2,3 replicate mats 0,1
    const int mt  = grp & 1;
    const float* __restrict__ mp = m2 + mt * 272;

    float b2[16];
    #pragma unroll
    for (int i = 0; i < 15; ++i) {
        const float p00 = mp[i * 17 + j2],       p01 = mp[i * 17 + j2 + 1];
        const float p10 = mp[(i + 1) * 17 + j2], p11 = mp[(i + 1) * 17 + j2 + 1];
        const float pv  = fmaxf(fmaxf(p00, p01), fmaxf(p10, p11));
        b2[i] = (j2 < 15) ? pv : 0.f;
    }
    b2[15] = 0.f;

    // Gershgorin shift from column abs sums (symmetric)
    float csum = 0.f;
    #pragma unroll
    for (int i = 0; i < 15; ++i) csum += fabsf(b2[i]);
    #pragma unroll
    for (int msk = 1; msk < 16; msk <<= 1)
        csum = fmaxf(csum, __shfl_xor(csum, msk));
    const float sigma = csum + 1.f;
    #pragma unroll
    for (int i = 0; i < 16; ++i) b2[i] += (i == j2) ? sigma : 0.f;

    float a2;
    {
        float s0 = 0.f, s1 = 0.f, s2 = 0.f, s3 = 0.f;
        #pragma unroll
        for (int r = 0; r < 16; r += 4) {
            s0 = fmaf(b2[r],   b2[r],   s0); s1 = fmaf(b2[r+1], b2[r+1], s1);
            s2 = fmaf(b2[r+2], b2[r+2], s2); s3 = fmaf(b2[r+3], b2[r+3], s3);
        }
        a2 = (s0 + s1) + (s2 + s3);
    }
    float f2 = 1.f, rf2 = 1.f;

    #pragma unroll 1
    for (int sweep = 0; sweep < SW2; ++sweep) {
        float offmax = -1.f;
        #pragma unroll 1
        for (int m = 1; m < 16; ++m) {
            const int hb = 31 - __clz(m);
            const bool isP = ((j2 >> hb) & 1) == 0;
            float pb[16];
            #pragma unroll
            for (int r = 0; r < 16; ++r) pb[r] = __shfl_xor(b2[r], m);
            float g0 = 0.f, g1 = 0.f, g2a = 0.f, g3 = 0.f;
            #pragma unroll
            for (int r = 0; r < 16; r += 4) {
                g0  = fmaf(b2[r],   pb[r],   g0);  g1 = fmaf(b2[r+1], pb[r+1], g1);
                g2a = fmaf(b2[r+2], pb[r+2], g2a); g3 = fmaf(b2[r+3], pb[r+3], g3);
            }
            const float gp = (g0 + g1) + (g2a + g3);
            const float fq = __shfl_xor(f2, m);
            const float aq = __shfl_xor(a2, m);
            const float gam = gp * (f2 * fq);
            const float d   = isP ? (aq - a2) : (a2 - aq);
            const float tg  = gam + gam;
            const float den = sqrtf(fmaf(d, d, tg * tg)) + fabsf(d) + 1e-30f;
            float t = __fdividef(tg, den);
            t = (d < 0.f) ? -t : t;
            const float e = fmaf(t, t, 1.f);
            const float c = rsqrtf(e);
            float coef = t * (fq * rf2);       // uses rf2 = 1/f2_old (THE FIX)
            coef = isP ? -coef : coef;
            f2  *= c;
            rf2 *= e * c;
            offmax = fmaxf(offmax, fmaf(gam, gam, -1e-12f * (a2 * aq)));
            #pragma unroll
            for (int r = 0; r < 16; ++r) b2[r] = fmaf(coef, pb[r], b2[r]);
            a2 = fmaf(isP ? -t : t, gam, a2);
        }
        #pragma unroll
        for (int r = 0; r < 16; ++r) b2[r] *= f2;
        {
            float s0 = 0.f, s1 = 0.f, s2 = 0.f, s3 = 0.f;
            #pragma unroll
            for (int r = 0; r < 16; r += 4) {
                s0 = fmaf(b2[r],   b2[r],   s0); s1 = fmaf(b2[r+1], b2[r+1], s1);
                s2 = fmaf(b2[r+2], b2[r+2], s2); s3 = fmaf(b2[r+3], b2[r+3], s3);
            }
            a2 = (s0 + s1) + (s2 + s3);
        }
        f2 = 1.f; rf2 = 1.f;
        if (__all(offmax <= 0.f)) break;
    }

    if (grp < 2) {
        #pragma unroll
        for (int r = 0; r < 16; ++r) B2s[mt * 272 + r * 17 + j2] = b2[r];
        w2s[mt * 16 + j2] = expf(sqrtf(a2) - sigma) / a2;   // exp(l)/l'^2
    }
    __syncthreads();

    // ---- out = B2 diag(w2) B2^T, 15x15 per matrix ----
    float* __restrict__ ob = out + matA * 225;
    #pragma unroll 1
    for (int idx = tid; idx < 450; idx += 64) {
        const int mm = (idx >= 225) ? 1 : 0;
        const int ii = idx - 225 * mm;
        const int oi = ii / 15, ok = ii % 15;
        const float* __restrict__ Bp = B2s + mm * 272;
        const float* __restrict__ wp = w2s + mm * 16;
        float acc = 0.f;
        #pragma unroll
        for (int cc = 0; cc < 16; ++cc)
            acc = fmaf(Bp[oi * 17 + cc] * wp[cc], Bp[ok * 17 + cc], acc);
        ob[idx] = acc;
    }
}

extern "C" void kernel_launch(void* const* d_in, const int* in_sizes, int n_in,
                              void* d_out, int out_size, void* d_ws, size_t ws_size,
                              hipStream_t stream)
{
    const float* x = (const float*)d_in[0];
    float* out = (float*)d_out;
    const int n_mat = in_sizes[0] / (32 * 32);   // 32768
    const int n_blk = n_mat / 2;                 // 2 matrices per 64-thread block
    dim3 grid(n_blk), block(64);
    hipLaunchKernelGGL(spd_logeig_pool_expeig, grid, block, 0, stream,
                       x, out, n_blk);
}

// Round 6
// 1921.370 us; speedup vs baseline: 3.4970x; 1.0409x over previous
//
#include <hip/hip_runtime.h>
#include <math.h>

// One 64-thread wave per TWO matrices (lanes 0-31: mat A, 32-63: mat B).
// Stage 1: one-sided Jacobi, full column per lane held as f32x2[16], XOR
//          pairing, v_pk_fma_f32 packed math, deferred column scaling,
//          early sweep exit. An empty-asm fence pins the shuffled partner
//          column in VGPRs (R5: compiler remat'd the 32 ds_bpermute,
//          doubling DS traffic — VGPR_Count 52 was the tell).
// Recon:   M = B diag(log(l)/l^2) B^T in 4x4 reg blocks, fused 2x2 pre-pool
//          maxes -> m2[16][17] (M never materialized).
// Stage 2: same machinery on P + sigma*I (Gershgorin shift), 16-lane groups.
// ExpEig:  out = B2 diag(exp(l'-sigma)/l'^2) B2^T, 15x15 per matrix.

typedef float f32x2 __attribute__((ext_vector_type(2)));

__device__ __forceinline__ f32x2 pkfma(f32x2 a, f32x2 b, f32x2 c) {
    f32x2 d;
    asm("v_pk_fma_f32 %0, %1, %2, %3" : "=v"(d) : "v"(a), "v"(b), "v"(c));
    return d;
}
__device__ __forceinline__ f32x2 pkadd(f32x2 a, f32x2 b) {
    f32x2 d;
    asm("v_pk_add_f32 %0, %1, %2" : "=v"(d) : "v"(a), "v"(b));
    return d;
}
__device__ __forceinline__ f32x2 pkmul(f32x2 a, f32x2 b) {
    f32x2 d;
    asm("v_pk_mul_f32 %0, %1, %2" : "=v"(d) : "v"(a), "v"(b));
    return d;
}

constexpr int SW1 = 10;   // max sweeps stage 1 (early exit typical ~6-7)
constexpr int SW2 = 8;    // max sweeps stage 2

__global__ __launch_bounds__(64, 4)
void spd_logeig_pool_expeig(const float* __restrict__ x,
                            float* __restrict__ out, int n_blk)
{
    __shared__ float Bl[2 * 1056];   // [2][32*33] stage-1 columns (overlaid later)
    __shared__ float m2[2 * 272];    // [2][16*17] 2x2 block maxes
    __shared__ float wl[2 * 32];     // stage-1 weights

    float* const B2s = Bl;           // overlay: [2][16*17] stage-2 columns
    float* const w2s = Bl + 544;     // overlay: [2][16]   stage-2 weights

    const int tid  = threadIdx.x;
    const int j    = tid & 31;
    const int half = tid >> 5;
    const size_t matA = (size_t)blockIdx.x * 2;
    const float* __restrict__ xm = x + (matA + half) * 1024;

    // ---- load column j of this half's matrix ----
    f32x2 b[16];
    #pragma unroll
    for (int r = 0; r < 16; ++r) {
        b[r].x = xm[(2 * r) * 32 + j];
        b[r].y = xm[(2 * r + 1) * 32 + j];
    }

    float alpha;
    {
        f32x2 g0 = {0.f, 0.f}, g1 = {0.f, 0.f}, g2 = {0.f, 0.f}, g3 = {0.f, 0.f};
        #pragma unroll
        for (int r = 0; r < 16; r += 4) {
            g0 = pkfma(b[r],   b[r],   g0); g1 = pkfma(b[r+1], b[r+1], g1);
            g2 = pkfma(b[r+2], b[r+2], g2); g3 = pkfma(b[r+3], b[r+3], g3);
        }
        const f32x2 gs = pkadd(pkadd(g0, g1), pkadd(g2, g3));
        alpha = gs.x + gs.y;
    }
    float f = 1.f, rf = 1.f;   // deferred column scale f and rf = 1/f

    // ---------------- stage 1: one-sided Jacobi, n=32 ----------------
    #pragma unroll 1
    for (int sweep = 0; sweep < SW1; ++sweep) {
        float offmax = -1.f;
        #pragma unroll 1
        for (int m = 1; m < 32; ++m) {
            const int hb = 31 - __clz(m);
            const bool isP = ((j >> hb) & 1) == 0;
            f32x2 pb[16];
            #pragma unroll
            for (int r = 0; r < 16; ++r) {
                pb[r].x = __shfl_xor(b[r].x, m);
                pb[r].y = __shfl_xor(b[r].y, m);
            }
            // pin shuffles in VGPRs: forbid remat/recompute before the update
            #pragma unroll
            for (int r = 0; r < 16; ++r) asm("" : "+v"(pb[r]));
            f32x2 g0 = {0.f,0.f}, g1 = {0.f,0.f}, g2 = {0.f,0.f}, g3 = {0.f,0.f};
            #pragma unroll
            for (int r = 0; r < 16; r += 4) {
                g0 = pkfma(b[r],   pb[r],   g0); g1 = pkfma(b[r+1], pb[r+1], g1);
                g2 = pkfma(b[r+2], pb[r+2], g2); g3 = pkfma(b[r+3], pb[r+3], g3);
            }
            const f32x2 gs = pkadd(pkadd(g0, g1), pkadd(g2, g3));
            const float gp = gs.x + gs.y;
            const float fq = __shfl_xor(f, m);
            const float aq = __shfl_xor(alpha, m);
            // gam/d bitwise-identical on both lanes of the pair
            const float gam = gp * (f * fq);
            const float d   = isP ? (aq - alpha) : (alpha - aq);
            const float tg  = gam + gam;
            const float den = sqrtf(fmaf(d, d, tg * tg)) + fabsf(d) + 1e-30f;
            float t = __fdividef(tg, den);
            t = (d < 0.f) ? -t : t;
            const float e = fmaf(t, t, 1.f);
            const float c = rsqrtf(e);
            float coef = t * (fq * rf);        // uses rf = 1/f_old (order matters!)
            coef = isP ? -coef : coef;
            f  *= c;                           // f_new = c * f_old
            rf *= e * c;                       // rf_new = rf_old / c
            offmax = fmaxf(offmax, fmaf(gam, gam, -1e-12f * (alpha * aq)));
            const f32x2 c2 = {coef, coef};
            #pragma unroll
            for (int r = 0; r < 16; ++r) b[r] = pkfma(c2, pb[r], b[r]);
            alpha = fmaf(isP ? -t : t, gam, alpha);
        }
        // fold deferred scale, refresh true alpha
        const f32x2 fs = {f, f};
        #pragma unroll
        for (int r = 0; r < 16; ++r) b[r] = pkmul(b[r], fs);
        {
            f32x2 g0 = {0.f,0.f}, g1 = {0.f,0.f}, g2 = {0.f,0.f}, g3 = {0.f,0.f};
            #pragma unroll
            for (int r = 0; r < 16; r += 4) {
                g0 = pkfma(b[r],   b[r],   g0); g1 = pkfma(b[r+1], b[r+1], g1);
                g2 = pkfma(b[r+2], b[r+2], g2); g3 = pkfma(b[r+3], b[r+3], g3);
            }
            const f32x2 gs = pkadd(pkadd(g0, g1), pkadd(g2, g3));
            alpha = gs.x + gs.y;
        }
        f = 1.f; rf = 1.f;
        if (__all(offmax <= 0.f)) break;
    }

    // ---- write columns + weights ----
    #pragma unroll
    for (int r = 0; r < 16; ++r) {
        Bl[half * 1056 + (2 * r)     * 33 + j] = b[r].x;
        Bl[half * 1056 + (2 * r + 1) * 33 + j] = b[r].y;
    }
    wl[half * 32 + j] = 0.5f * logf(alpha) / alpha;   // log(l)/l^2, l=sqrt(a)
    __syncthreads();

    // ---- M = B diag(w) B^T, 4x4 reg blocks, fused 2x2 pre-pool ----
    {
        const int bi = tid >> 3, bj = tid & 7;
        #pragma unroll 1
        for (int mm = 0; mm < 2; ++mm) {
            const float* __restrict__ B = Bl + mm * 1056;
            const float* __restrict__ w = wl + mm * 32;
            float acc[4][4];
            #pragma unroll
            for (int a = 0; a < 4; ++a)
                #pragma unroll
                for (int cc = 0; cc < 4; ++cc) acc[a][cc] = 0.f;
            #pragma unroll 2
            for (int k = 0; k < 32; ++k) {
                const float wk = w[k];
                float vi[4], vj[4];
                #pragma unroll
                for (int a = 0; a < 4; ++a)  vi[a] = B[(bi * 4 + a) * 33 + k] * wk;
                #pragma unroll
                for (int cc = 0; cc < 4; ++cc) vj[cc] = B[(bj * 4 + cc) * 33 + k];
                #pragma unroll
                for (int a = 0; a < 4; ++a)
                    #pragma unroll
                    for (int cc = 0; cc < 4; ++cc)
                        acc[a][cc] = fmaf(vi[a], vj[cc], acc[a][cc]);
            }
            #pragma unroll
            for (int u = 0; u < 2; ++u)
                #pragma unroll
                for (int v = 0; v < 2; ++v) {
                    const float mx =
                        fmaxf(fmaxf(acc[2*u][2*v],   acc[2*u][2*v+1]),
                              fmaxf(acc[2*u+1][2*v], acc[2*u+1][2*v+1]));
                    m2[mm * 272 + (2 * bi + u) * 17 + (2 * bj + v)] = mx;
                }
        }
    }
    __syncthreads();

    // ---------------- stage 2: n=16 (col 15 = zero dummy) ----------------
    const int j2  = tid & 15;
    const int grp = tid >> 4;            // groups 2,3 replicate mats 0,1
    const int mt  = grp & 1;
    const float* __restrict__ mp = m2 + mt * 272;

    float t16[16];
    #pragma unroll
    for (int i = 0; i < 15; ++i) {
        const float p00 = mp[i * 17 + j2],       p01 = mp[i * 17 + j2 + 1];
        const float p10 = mp[(i + 1) * 17 + j2], p11 = mp[(i + 1) * 17 + j2 + 1];
        const float pv  = fmaxf(fmaxf(p00, p01), fmaxf(p10, p11));
        t16[i] = (j2 < 15) ? pv : 0.f;
    }
    t16[15] = 0.f;

    // Gershgorin shift from column abs sums (symmetric)
    float csum = 0.f;
    #pragma unroll
    for (int i = 0; i < 15; ++i) csum += fabsf(t16[i]);
    #pragma unroll
    for (int msk = 1; msk < 16; msk <<= 1)
        csum = fmaxf(csum, __shfl_xor(csum, msk));
    const float sigma = csum + 1.f;
    t16[0]  += (j2 == 0)  ? sigma : 0.f;   // diagonal add, unrolled below
    #pragma unroll
    for (int i = 1; i < 16; ++i) t16[i] += (i == j2) ? sigma : 0.f;

    f32x2 q[8];
    #pragma unroll
    for (int r = 0; r < 8; ++r) { q[r].x = t16[2 * r]; q[r].y = t16[2 * r + 1]; }

    float a2;
    {
        f32x2 g0 = {0.f,0.f}, g1 = {0.f,0.f};
        #pragma unroll
        for (int r = 0; r < 8; r += 2) {
            g0 = pkfma(q[r],   q[r],   g0);
            g1 = pkfma(q[r+1], q[r+1], g1);
        }
        const f32x2 gs = pkadd(g0, g1);
        a2 = gs.x + gs.y;
    }
    float f2 = 1.f, rf2 = 1.f;

    #pragma unroll 1
    for (int sweep = 0; sweep < SW2; ++sweep) {
        float offmax = -1.f;
        #pragma unroll 1
        for (int m = 1; m < 16; ++m) {
            const int hb = 31 - __clz(m);
            const bool isP = ((j2 >> hb) & 1) == 0;
            f32x2 pb[8];
            #pragma unroll
            for (int r = 0; r < 8; ++r) {
                pb[r].x = __shfl_xor(q[r].x, m);
                pb[r].y = __shfl_xor(q[r].y, m);
            }
            #pragma unroll
            for (int r = 0; r < 8; ++r) asm("" : "+v"(pb[r]));
            f32x2 g0 = {0.f,0.f}, g1 = {0.f,0.f};
            #pragma unroll
            for (int r = 0; r < 8; r += 2) {
                g0 = pkfma(q[r],   pb[r],   g0);
                g1 = pkfma(q[r+1], pb[r+1], g1);
            }
            const f32x2 gs = pkadd(g0, g1);
            const float gp = gs.x + gs.y;
            const float fq = __shfl_xor(f2, m);
            const float aq = __shfl_xor(a2, m);
            const float gam = gp * (f2 * fq);
            const float d   = isP ? (aq - a2) : (a2 - aq);
            const float tg  = gam + gam;
            const float den = sqrtf(fmaf(d, d, tg * tg)) + fabsf(d) + 1e-30f;
            float t = __fdividef(tg, den);
            t = (d < 0.f) ? -t : t;
            const float e = fmaf(t, t, 1.f);
            const float c = rsqrtf(e);
            float coef = t * (fq * rf2);       // rf2 = 1/f2_old (order matters!)
            coef = isP ? -coef : coef;
            f2  *= c;
            rf2 *= e * c;
            offmax = fmaxf(offmax, fmaf(gam, gam, -1e-12f * (a2 * aq)));
            const f32x2 c2 = {coef, coef};
            #pragma unroll
            for (int r = 0; r < 8; ++r) q[r] = pkfma(c2, pb[r], q[r]);
            a2 = fmaf(isP ? -t : t, gam, a2);
        }
        const f32x2 fs = {f2, f2};
        #pragma unroll
        for (int r = 0; r < 8; ++r) q[r] = pkmul(q[r], fs);
        {
            f32x2 g0 = {0.f,0.f}, g1 = {0.f,0.f};
            #pragma unroll
            for (int r = 0; r < 8; r += 2) {
                g0 = pkfma(q[r],   q[r],   g0);
                g1 = pkfma(q[r+1], q[r+1], g1);
            }
            const f32x2 gs = pkadd(g0, g1);
            a2 = gs.x + gs.y;
        }
        f2 = 1.f; rf2 = 1.f;
        if (__all(offmax <= 0.f)) break;
    }

    if (grp < 2) {
        #pragma unroll
        for (int r = 0; r < 8; ++r) {
            B2s[mt * 272 + (2 * r)     * 17 + j2] = q[r].x;
            B2s[mt * 272 + (2 * r + 1) * 17 + j2] = q[r].y;
        }
        w2s[mt * 16 + j2] = expf(sqrtf(a2) - sigma) / a2;   // exp(l)/l'^2
    }
    __syncthreads();

    // ---- out = B2 diag(w2) B2^T, 15x15 per matrix ----
    float* __restrict__ ob = out + matA * 225;
    #pragma unroll 1
    for (int idx = tid; idx < 450; idx += 64) {
        const int mm = (idx >= 225) ? 1 : 0;
        const int ii = idx - 225 * mm;
        const int oi = ii / 15, ok = ii % 15;
        const float* __restrict__ Bp = B2s + mm * 272;
        const float* __restrict__ wp = w2s + mm * 16;
        float acc = 0.f;
        #pragma unroll
        for (int cc = 0; cc < 16; ++cc)
            acc = fmaf(Bp[oi * 17 + cc] * wp[cc], Bp[ok * 17 + cc], acc);
        ob[idx] = acc;
    }
}

extern "C" void kernel_launch(void* const* d_in, const int* in_sizes, int n_in,
                              void* d_out, int out_size, void* d_ws, size_t ws_size,
                              hipStream_t stream)
{
    const float* x = (const float*)d_in[0];
    float* out = (float*)d_out;
    const int n_mat = in_sizes[0] / (32 * 32);   // 32768
    const int n_blk = n_mat / 2;                 // 2 matrices per 64-thread block
    dim3 grid(n_blk), block(64);
    hipLaunchKernelGGL(spd_logeig_pool_expeig, grid, block, 0, stream,
                       x, out, n_blk);
}

// Round 7
// 1494.238 us; speedup vs baseline: 4.4966x; 1.2859x over previous
//
#include <hip/hip_runtime.h>
#include <math.h>

// One 64-thread wave per FOUR matrices. Group g = lanes 16g..16g+15 owns one
// 32x32 SPD matrix; lane u in the group holds columns (2u, 2u+1) packed as
// f32x2[32].  Block one-sided Jacobi: per sweep, 1 in-lane rotation
// (cols 2u,2u+1 — zero DS) + 15 cross rounds. A cross round exchanges the
// partner lane's TWO columns once (64 ds_bpermute) and performs FOUR
// rotations in 2 disjoint packed phases -> 0.53 DS-inst/rotation vs 1.0
// before (R6 was DS-pipe-bound: ~1M DS insts/CU ~= the whole runtime).
// Rotation params are bitwise-identical across the lane pair: commutative
// multiplies, identical accumulation trees, tmp-direct updates (my local
// copy of the partner column bit-matches the partner's own update).
// Recon: 2 passes (mat pairs) through a 2-slot LDS buffer, pair-packed
// ds_b64; fused 2x2 pre-pool -> m2. Stage 2: n=16 Jacobi per 16-lane group
// (4 real mats, no redundancy), deferred-scaling machinery from R6 (proven).
// ExpEig epilogue -> 15x15 per matrix.

typedef float f32x2 __attribute__((ext_vector_type(2)));

__device__ __forceinline__ f32x2 pkfma(f32x2 a, f32x2 b, f32x2 c) {
    f32x2 d; asm("v_pk_fma_f32 %0, %1, %2, %3" : "=v"(d) : "v"(a), "v"(b), "v"(c));
    return d;
}
// d = a * swap(b) + c   (lo: a.x*b.y + c.x ; hi: a.y*b.x + c.y)
__device__ __forceinline__ f32x2 pkfma_s1(f32x2 a, f32x2 b, f32x2 c) {
    f32x2 d; asm("v_pk_fma_f32 %0, %1, %2, %3 op_sel:[0,1,0] op_sel_hi:[1,0,1]"
                 : "=v"(d) : "v"(a), "v"(b), "v"(c));
    return d;
}
__device__ __forceinline__ f32x2 pkmul(f32x2 a, f32x2 b) {
    f32x2 d; asm("v_pk_mul_f32 %0, %1, %2" : "=v"(d) : "v"(a), "v"(b));
    return d;
}
__device__ __forceinline__ f32x2 pkadd(f32x2 a, f32x2 b) {
    f32x2 d; asm("v_pk_add_f32 %0, %1, %2" : "=v"(d) : "v"(a), "v"(b));
    return d;
}
__device__ __forceinline__ float bperm(int addr, float v) {
    return __int_as_float(__builtin_amdgcn_ds_bpermute(addr, __float_as_int(v)));
}

constexpr int SW1 = 10;   // max sweeps stage 1 (early exit typical ~6-7)
constexpr int SW2 = 8;    // max sweeps stage 2

__global__ __launch_bounds__(64, 2)
void spd_logeig_pool_expeig(const float* __restrict__ x,
                            float* __restrict__ out, int n_blk)
{
    __shared__ f32x2 Bl2[2][32][17];   // 2 mat slots, pair-packed columns
    __shared__ f32x2 wwl[2][16];       // packed weights for resident slots
    __shared__ float m2s[4][272];      // [4 mats][16*17] 2x2 block maxes
    __shared__ float B2s[4][272];      // stage-2 columns
    __shared__ float w2s[4][16];       // stage-2 weights

    const int tid = threadIdx.x;
    const int u   = tid & 15;          // lane within group
    const int g   = tid >> 4;          // group = matrix
    const size_t mat0 = (size_t)blockIdx.x * 4;
    const float* __restrict__ xm = x + (mat0 + g) * 1024;

    // ---- load columns 2u, 2u+1 (one b64 per row, coalesced) ----
    f32x2 q[32];
    #pragma unroll
    for (int r = 0; r < 32; ++r)
        q[r] = *reinterpret_cast<const f32x2*>(xm + r * 32 + 2 * u);

    f32x2 A;   // (||col 2u||^2, ||col 2u+1||^2)
    {
        f32x2 a0={0.f,0.f}, a1={0.f,0.f}, a2={0.f,0.f}, a3={0.f,0.f};
        #pragma unroll
        for (int r = 0; r < 32; r += 4) {
            a0 = pkfma(q[r],   q[r],   a0); a1 = pkfma(q[r+1], q[r+1], a1);
            a2 = pkfma(q[r+2], q[r+2], a2); a3 = pkfma(q[r+3], q[r+3], a3);
        }
        A = pkadd(pkadd(a0, a1), pkadd(a2, a3));
    }

    // ================= stage 1: block one-sided Jacobi, n=32 =================
    #pragma unroll 1
    for (int sweep = 0; sweep < SW1; ++sweep) {
        float offmax = -1.f;

        // ---- in-lane rotation: pair (2u, 2u+1), p = 2u always ----
        {
            f32x2 a0={0.f,0.f}, a1={0.f,0.f};
            #pragma unroll
            for (int r = 0; r < 32; r += 2) {
                a0 = pkfma_s1(q[r],   q[r],   a0);   // q.x*q.y accum
                a1 = pkfma_s1(q[r+1], q[r+1], a1);
            }
            const float gam = pkadd(a0, a1).x;
            const float d   = A.y - A.x;
            const float tg  = gam + gam;
            const float den = sqrtf(fmaf(d, d, tg * tg)) + fabsf(d) + 1e-30f;
            float t = __fdividef(tg, den);
            t = (d < 0.f) ? -t : t;
            const float c = rsqrtf(fmaf(t, t, 1.f));
            const float s = t * c;
            offmax = fmaxf(offmax, fmaf(gam, gam, -1e-12f * (A.x * A.y)));
            const f32x2 C1 = {c, c}, C2 = {-s, s};
            #pragma unroll
            for (int r = 0; r < 32; ++r)
                q[r] = pkfma_s1(C2, q[r], pkmul(C1, q[r]));
            const f32x2 sT = {-t, t}, G0 = {gam, gam};
            A = pkfma(sT, G0, A);                 // alpha_p -= t g, alpha_q += t g
        }

        // ---- cross rounds: partner lane u^m, 4 rotations per exchange ----
        #pragma unroll 1
        for (int m = 1; m < 16; ++m) {
            const int  paddr = (tid ^ m) << 2;
            const bool isP   = (u < (u ^ m));
            f32x2 pb[32];
            #pragma unroll
            for (int r = 0; r < 32; ++r) {
                pb[r].x = bperm(paddr, q[r].x);
                pb[r].y = bperm(paddr, q[r].y);
            }
            f32x2 Aq;
            Aq.x = bperm(paddr, A.x);
            Aq.y = bperm(paddr, A.y);
            // grouped pins: asm defs cannot be rematerialized -> exactly one
            // shuffle per element per round (R5/R6: per-elem pins failed)
            asm("" : "+v"(pb[0]),"+v"(pb[1]),"+v"(pb[2]),"+v"(pb[3]),
                     "+v"(pb[4]),"+v"(pb[5]),"+v"(pb[6]),"+v"(pb[7]));
            asm("" : "+v"(pb[8]),"+v"(pb[9]),"+v"(pb[10]),"+v"(pb[11]),
                     "+v"(pb[12]),"+v"(pb[13]),"+v"(pb[14]),"+v"(pb[15]));
            asm("" : "+v"(pb[16]),"+v"(pb[17]),"+v"(pb[18]),"+v"(pb[19]),
                     "+v"(pb[20]),"+v"(pb[21]),"+v"(pb[22]),"+v"(pb[23]));
            asm("" : "+v"(pb[24]),"+v"(pb[25]),"+v"(pb[26]),"+v"(pb[27]),
                     "+v"(pb[28]),"+v"(pb[29]),"+v"(pb[30]),"+v"(pb[31]),
                     "+v"(Aq));

            // ---- phase 1: disjoint pairs (2u,2v) & (2u+1,2v+1), v=u^m ----
            f32x2 G;
            {
                f32x2 a0={0.f,0.f}, a1={0.f,0.f}, a2={0.f,0.f}, a3={0.f,0.f};
                #pragma unroll
                for (int r = 0; r < 32; r += 4) {
                    a0 = pkfma(q[r],   pb[r],   a0);
                    a1 = pkfma(q[r+1], pb[r+1], a1);
                    a2 = pkfma(q[r+2], pb[r+2], a2);
                    a3 = pkfma(q[r+3], pb[r+3], a3);
                }
                G = pkadd(pkadd(a0, a1), pkadd(a2, a3));
            }
            f32x2 d2 = Aq - A;
            if (!isP) d2 = A - Aq;
            float t0, c0, t1, c1;
            {
                const float gam = G.x, d = d2.x, tg = gam + gam;
                const float den = sqrtf(fmaf(d, d, tg * tg)) + fabsf(d) + 1e-30f;
                float t = __fdividef(tg, den); t = (d < 0.f) ? -t : t;
                t0 = t; c0 = rsqrtf(fmaf(t, t, 1.f));
                offmax = fmaxf(offmax, fmaf(gam, gam, -1e-12f * (A.x * Aq.x)));
            }
            {
                const float gam = G.y, d = d2.y, tg = gam + gam;
                const float den = sqrtf(fmaf(d, d, tg * tg)) + fabsf(d) + 1e-30f;
                float t = __fdividef(tg, den); t = (d < 0.f) ? -t : t;
                t1 = t; c1 = rsqrtf(fmaf(t, t, 1.f));
                offmax = fmaxf(offmax, fmaf(gam, gam, -1e-12f * (A.y * Aq.y)));
            }
            const f32x2 C  = {c0, c1};
            const f32x2 T  = {t0, t1};
            const f32x2 CT = pkmul(C, T);
            f32x2 CTo = CT; if (isP) CTo = -CT;   // own = p side -> -ct
            const f32x2 CTb = -CTo;
            #pragma unroll
            for (int r = 0; r < 32; ++r) {
                const f32x2 tq = q[r];
                q[r]  = pkfma(CTo, pb[r], pkmul(C, q[r]));
                pb[r] = pkfma(CTb, tq,    pkmul(C, pb[r]));   // == partner's own
            }
            f32x2 sT = T; if (isP) sT = -T;
            A  = pkfma(sT, G, A);
            Aq = pkfma(-sT, G, Aq);

            // ---- phase 2: swapped pairs (2u,2v+1) & (2u+1,2v); p-ness = isP ----
            f32x2 G2;
            {
                f32x2 a0={0.f,0.f}, a1={0.f,0.f}, a2={0.f,0.f}, a3={0.f,0.f};
                #pragma unroll
                for (int r = 0; r < 32; r += 4) {
                    a0 = pkfma_s1(q[r],   pb[r],   a0);   // q.x*pb.y / q.y*pb.x
                    a1 = pkfma_s1(q[r+1], pb[r+1], a1);
                    a2 = pkfma_s1(q[r+2], pb[r+2], a2);
                    a3 = pkfma_s1(q[r+3], pb[r+3], a3);
                }
                G2 = pkadd(pkadd(a0, a1), pkadd(a2, a3));
            }
            const f32x2 Aq2 = {Aq.y, Aq.x};
            f32x2 e2 = Aq2 - A;
            if (!isP) e2 = A - Aq2;
            float t0b, c0b, t1b, c1b;
            {
                const float gam = G2.x, d = e2.x, tg = gam + gam;
                const float den = sqrtf(fmaf(d, d, tg * tg)) + fabsf(d) + 1e-30f;
                float t = __fdividef(tg, den); t = (d < 0.f) ? -t : t;
                t0b = t; c0b = rsqrtf(fmaf(t, t, 1.f));
                offmax = fmaxf(offmax, fmaf(gam, gam, -1e-12f * (A.x * Aq2.x)));
            }
            {
                const float gam = G2.y, d = e2.y, tg = gam + gam;
                const float den = sqrtf(fmaf(d, d, tg * tg)) + fabsf(d) + 1e-30f;
                float t = __fdividef(tg, den); t = (d < 0.f) ? -t : t;
                t1b = t; c1b = rsqrtf(fmaf(t, t, 1.f));
                offmax = fmaxf(offmax, fmaf(gam, gam, -1e-12f * (A.y * Aq2.y)));
            }
            const f32x2 C2v = {c0b, c1b};
            const f32x2 T2  = {t0b, t1b};
            const f32x2 CT2 = pkmul(C2v, T2);
            f32x2 CTo2 = CT2; if (isP) CTo2 = -CT2;
            #pragma unroll
            for (int r = 0; r < 32; ++r)
                q[r] = pkfma_s1(CTo2, pb[r], pkmul(C2v, q[r]));
            f32x2 sT2 = T2; if (isP) sT2 = -T2;
            A = pkfma(sT2, G2, A);
        }

        // ---- refresh true norms (kill drift) ----
        {
            f32x2 a0={0.f,0.f}, a1={0.f,0.f}, a2={0.f,0.f}, a3={0.f,0.f};
            #pragma unroll
            for (int r = 0; r < 32; r += 4) {
                a0 = pkfma(q[r],   q[r],   a0); a1 = pkfma(q[r+1], q[r+1], a1);
                a2 = pkfma(q[r+2], q[r+2], a2); a3 = pkfma(q[r+3], q[r+3], a3);
            }
            A = pkadd(pkadd(a0, a1), pkadd(a2, a3));
        }
        if (__all(offmax <= 0.f)) break;
    }

    // weights: w = log(l)/l^2 = 0.5*log(alpha)/alpha  (l = sqrt(alpha) >= 1)
    const f32x2 W = { 0.5f * logf(A.x) / A.x, 0.5f * logf(A.y) / A.y };

    // ========== recon M = B diag(w) B^T + fused 2x2 pre-pool, 2 passes ==========
    const int bi = (tid >> 3) & 7, bj = tid & 7;
    #pragma unroll 1
    for (int pass = 0; pass < 2; ++pass) {
        if ((g >> 1) == pass) {
            const int slot = g & 1;
            #pragma unroll
            for (int r = 0; r < 32; ++r) Bl2[slot][r][u] = q[r];
            wwl[slot][u] = W;
        }
        __syncthreads();
        #pragma unroll 1
        for (int slot = 0; slot < 2; ++slot) {
            f32x2 acc2[4][4];
            #pragma unroll
            for (int a = 0; a < 4; ++a)
                #pragma unroll
                for (int cc = 0; cc < 4; ++cc) acc2[a][cc] = (f32x2){0.f, 0.f};
            #pragma unroll 2
            for (int k = 0; k < 16; ++k) {
                const f32x2 W2 = wwl[slot][k];
                f32x2 vi[4], vj[4];
                #pragma unroll
                for (int a = 0; a < 4; ++a)
                    vi[a] = pkmul(W2, Bl2[slot][bi * 4 + a][k]);
                #pragma unroll
                for (int cc = 0; cc < 4; ++cc)
                    vj[cc] = Bl2[slot][bj * 4 + cc][k];
                #pragma unroll
                for (int a = 0; a < 4; ++a)
                    #pragma unroll
                    for (int cc = 0; cc < 4; ++cc)
                        acc2[a][cc] = pkfma(vi[a], vj[cc], acc2[a][cc]);
            }
            #pragma unroll
            for (int u2 = 0; u2 < 2; ++u2)
                #pragma unroll
                for (int v2 = 0; v2 < 2; ++v2) {
                    const float e00 = acc2[2*u2][2*v2].x     + acc2[2*u2][2*v2].y;
                    const float e01 = acc2[2*u2][2*v2+1].x   + acc2[2*u2][2*v2+1].y;
                    const float e10 = acc2[2*u2+1][2*v2].x   + acc2[2*u2+1][2*v2].y;
                    const float e11 = acc2[2*u2+1][2*v2+1].x + acc2[2*u2+1][2*v2+1].y;
                    m2s[pass * 2 + slot][(2 * bi + u2) * 17 + (2 * bj + v2)] =
                        fmaxf(fmaxf(e00, e01), fmaxf(e10, e11));
                }
        }
        __syncthreads();
    }

    // ================= stage 2: n=16 per group (col 15 = zero dummy) =================
    const float* __restrict__ mp = m2s[g];
    float t16[16];
    #pragma unroll
    for (int i = 0; i < 15; ++i) {
        const float p00 = mp[i * 17 + u],       p01 = mp[i * 17 + u + 1];
        const float p10 = mp[(i + 1) * 17 + u], p11 = mp[(i + 1) * 17 + u + 1];
        const float pv  = fmaxf(fmaxf(p00, p01), fmaxf(p10, p11));
        t16[i] = (u < 15) ? pv : 0.f;
    }
    t16[15] = 0.f;

    float csum = 0.f;
    #pragma unroll
    for (int i = 0; i < 15; ++i) csum += fabsf(t16[i]);
    #pragma unroll
    for (int msk = 1; msk < 16; msk <<= 1)
        csum = fmaxf(csum, __shfl_xor(csum, msk));
    const float sigma = csum + 1.f;
    #pragma unroll
    for (int i = 0; i < 16; ++i) t16[i] += (i == u) ? sigma : 0.f;

    f32x2 qq[8];
    #pragma unroll
    for (int r = 0; r < 8; ++r) { qq[r].x = t16[2 * r]; qq[r].y = t16[2 * r + 1]; }

    float a2;
    {
        f32x2 g0 = {0.f,0.f}, g1 = {0.f,0.f};
        #pragma unroll
        for (int r = 0; r < 8; r += 2) {
            g0 = pkfma(qq[r],   qq[r],   g0);
            g1 = pkfma(qq[r+1], qq[r+1], g1);
        }
        const f32x2 gs = pkadd(g0, g1);
        a2 = gs.x + gs.y;
    }
    float f2 = 1.f, rf2 = 1.f;

    #pragma unroll 1
    for (int sweep = 0; sweep < SW2; ++sweep) {
        float offmax = -1.f;
        #pragma unroll 1
        for (int m = 1; m < 16; ++m) {
            const int  paddr = (tid ^ m) << 2;
            const bool isP   = (u < (u ^ m));
            f32x2 pb2[8];
            #pragma unroll
            for (int r = 0; r < 8; ++r) {
                pb2[r].x = bperm(paddr, qq[r].x);
                pb2[r].y = bperm(paddr, qq[r].y);
            }
            float fq = bperm(paddr, f2);
            float aq = bperm(paddr, a2);
            asm("" : "+v"(pb2[0]),"+v"(pb2[1]),"+v"(pb2[2]),"+v"(pb2[3]),
                     "+v"(pb2[4]),"+v"(pb2[5]),"+v"(pb2[6]),"+v"(pb2[7]),
                     "+v"(fq), "+v"(aq));
            f32x2 g0 = {0.f,0.f}, g1 = {0.f,0.f};
            #pragma unroll
            for (int r = 0; r < 8; r += 2) {
                g0 = pkfma(qq[r],   pb2[r],   g0);
                g1 = pkfma(qq[r+1], pb2[r+1], g1);
            }
            const f32x2 gs = pkadd(g0, g1);
            const float gp = gs.x + gs.y;
            const float gam = gp * (f2 * fq);
            const float d   = isP ? (aq - a2) : (a2 - aq);
            const float tg  = gam + gam;
            const float den = sqrtf(fmaf(d, d, tg * tg)) + fabsf(d) + 1e-30f;
            float t = __fdividef(tg, den);
            t = (d < 0.f) ? -t : t;
            const float e = fmaf(t, t, 1.f);
            const float c = rsqrtf(e);
            float coef = t * (fq * rf2);        // rf2 = 1/f2_old (order matters!)
            coef = isP ? -coef : coef;
            f2  *= c;
            rf2 *= e * c;
            offmax = fmaxf(offmax, fmaf(gam, gam, -1e-12f * (a2 * aq)));
            const f32x2 c2 = {coef, coef};
            #pragma unroll
            for (int r = 0; r < 8; ++r) qq[r] = pkfma(c2, pb2[r], qq[r]);
            a2 = fmaf(isP ? -t : t, gam, a2);
        }
        const f32x2 fs = {f2, f2};
        #pragma unroll
        for (int r = 0; r < 8; ++r) qq[r] = pkmul(qq[r], fs);
        {
            f32x2 g0 = {0.f,0.f}, g1 = {0.f,0.f};
            #pragma unroll
            for (int r = 0; r < 8; r += 2) {
                g0 = pkfma(qq[r],   qq[r],   g0);
                g1 = pkfma(qq[r+1], qq[r+1], g1);
            }
            const f32x2 gs = pkadd(g0, g1);
            a2 = gs.x + gs.y;
        }
        f2 = 1.f; rf2 = 1.f;
        if (__all(offmax <= 0.f)) break;
    }

    #pragma unroll
    for (int r = 0; r < 8; ++r) {
        B2s[g][(2 * r) * 17 + u]     = qq[r].x;
        B2s[g][(2 * r + 1) * 17 + u] = qq[r].y;
    }
    w2s[g][u] = expf(sqrtf(a2) - sigma) / a2;     // exp(l)/l'^2
    __syncthreads();

    // ---- out = B2 diag(w2) B2^T, 15x15 per matrix ----
    float* __restrict__ ob = out + mat0 * 225;
    #pragma unroll 1
    for (int idx = tid; idx < 900; idx += 64) {
        const int mm = idx / 225;
        const int ii = idx - 225 * mm;
        const int oi = ii / 15, ok = ii - 15 * oi;
        float acc = 0.f;
        #pragma unroll
        for (int cc = 0; cc < 16; ++cc)
            acc = fmaf(B2s[mm][oi * 17 + cc] * w2s[mm][cc],
                       B2s[mm][ok * 17 + cc], acc);
        ob[idx] = acc;
    }
}

extern "C" void kernel_launch(void* const* d_in, const int* in_sizes, int n_in,
                              void* d_out, int out_size, void* d_ws, size_t ws_size,
                              hipStream_t stream)
{
    const float* x = (const float*)d_in[0];
    float* out = (float*)d_out;
    const int n_mat = in_sizes[0] / (32 * 32);   // 32768
    const int n_blk = n_mat / 4;                 // 4 matrices per 64-thread block
    dim3 grid(n_blk), block(64);
    hipLaunchKernelGGL(spd_logeig_pool_expeig, grid, block, 0, stream,
                       x, out, n_blk);
}